// Round 11
// baseline (379.604 us; speedup 1.0000x reference)
//
#include <hip/hip_runtime.h>
#include <hip/hip_bf16.h>

#define EMB 128
#define HID 11
#define PAIRS 2   // token-pairs per pipeline stage (4 tokens/stage)
#define REPS 4    // DIAGNOSTIC: idempotent x4 repeat so this kernel lands in
                  // rocprof's top-5 (fills run ~240us; we need >250us) with
                  // steady-state counters at TRUE occupancy. Remove next round.

typedef float f32x4 __attribute__((ext_vector_type(4)));

// tanh(x) = sign(x) * (1 - 2/(exp(2|x|)+1)); v_exp_f32 + v_rcp_f32 fast path.
__device__ __forceinline__ float fast_tanh(float x) {
    float ax = fabsf(x);
    float e  = __expf(2.0f * ax);
    float r  = 1.0f - 2.0f * __builtin_amdgcn_rcpf(e + 1.0f);
    return copysignf(r, x);
}

// Locked-in: STRIDED token->wave map (R6), NT stores for out_sum (R7),
// no tight VGPR cap (R3). Structure = R5 best (95.5us): PAIRS=2, depth-1
// software pipeline, fused out_pm store.
__global__ __launch_bounds__(256, 2) void tabenc_kernel(
    const float* __restrict__ value,
    const int*   __restrict__ var_id,
    const int*   __restrict__ cmask,
    const float* __restrict__ W1,
    const float* __restrict__ b1,
    const float* __restrict__ W2,
    const float* __restrict__ emb,
    float*       __restrict__ out_sum,
    float*       __restrict__ out_pm,
    int n_tokens)
{
    const int tid  = threadIdx.x;
    const int lane = tid & 63;
    const int half = lane >> 5;
    const int sub  = lane & 31;
    const int sb   = lane & 32;      // shfl source base for this half-wave
    const int c0   = sub << 2;

    f32x4 w2[HID];
#pragma unroll
    for (int h = 0; h < HID; ++h)
        w2[h] = *reinterpret_cast<const f32x4*>(W2 + h * EMB + c0);

    float w1v = 0.0f, b1v = 0.0f;
    if (sub < HID) { w1v = W1[sub]; b1v = b1[sub]; }

    const int gwave  = (blockIdx.x << 2) + (tid >> 6);
    const int nwaves = gridDim.x << 2;
    const int nwS    = nwaves * PAIRS;      // stage stride in pair-index space
    const int npair  = (n_tokens + 1) >> 1;
    const int tmax   = n_tokens - 1;

    if (gwave >= npair) return;

    int   tokC[PAIRS]; bool actC[PAIRS]; float vC[PAIRS];
    int   idC[PAIRS];  float fmC[PAIRS];  f32x4 eC[PAIRS];
    int   tokN[PAIRS]; bool actN[PAIRS]; float vN[PAIRS];
    int   idN[PAIRS];  float fmN[PAIRS];  f32x4 eN[PAIRS];

    auto LOAD = [&](int wbase, int* tok, bool* act, float* v, int* id,
                    float* fm, f32x4* e) {
#pragma unroll
        for (int k = 0; k < PAIRS; ++k) {
            const int wk = wbase + k * nwaves;
            act[k] = (wk < npair);
            int t = 2 * wk + half;
            if (t > tmax) t = tmax;     // clamp: branch-free, dup loads only
            tok[k] = t;
            v[k]  = value[t];
            id[k] = var_id[t];
            fm[k] = (float)cmask[t];
        }
#pragma unroll
        for (int k = 0; k < PAIRS; ++k)
            e[k] = *reinterpret_cast<const f32x4*>(emb + (long)id[k] * EMB + c0);
    };

    for (int rep = 0; rep < REPS; ++rep) {
        LOAD(gwave, tokC, actC, vC, idC, fmC, eC);

        for (int w = gwave; w < npair; w += nwS) {
            // ---- prefetch next stage (clamped, unconditional) ----
            LOAD(w + nwS, tokN, actN, vN, idN, fmN, eN);

            // ---- compute current stage ----
            float hv[PAIRS];
#pragma unroll
            for (int k = 0; k < PAIRS; ++k)
                hv[k] = fast_tanh(fmaf(vC[k], w1v, b1v));

            f32x4 acc[PAIRS];
#pragma unroll
            for (int k = 0; k < PAIRS; ++k)
                acc[k] = (f32x4){0.f, 0.f, 0.f, 0.f};

#pragma unroll
            for (int hh = 0; hh < HID; ++hh) {
#pragma unroll
                for (int k = 0; k < PAIRS; ++k) {
                    const float kk = __shfl(hv[k], sb + hh, 64);
                    acc[k] += kk * w2[hh];
                }
            }

#pragma unroll
            for (int k = 0; k < PAIRS; ++k) {
                if (actC[k]) {
                    const f32x4 o = acc[k] * fmC[k] + eC[k];
                    __builtin_nontemporal_store(o,
                        reinterpret_cast<f32x4*>(out_sum + (long)tokC[k] * EMB + c0));
                    if (sub == 0)
                        out_pm[tokC[k]] = (idC[k] > 0) ? 1.0f : 0.0f;
                }
            }

            // ---- rotate pipeline regs ----
#pragma unroll
            for (int k = 0; k < PAIRS; ++k) {
                tokC[k] = tokN[k]; actC[k] = actN[k]; vC[k] = vN[k];
                idC[k]  = idN[k];  fmC[k]  = fmN[k];  eC[k] = eN[k];
            }
        }
    }
}

extern "C" void kernel_launch(void* const* d_in, const int* in_sizes, int n_in,
                              void* d_out, int out_size, void* d_ws, size_t ws_size,
                              hipStream_t stream) {
    const float* value  = (const float*)d_in[0];
    const int*   var_id = (const int*)  d_in[1];
    const int*   cmask  = (const int*)  d_in[2];
    const float* W1     = (const float*)d_in[3];
    const float* b1     = (const float*)d_in[4];
    const float* W2     = (const float*)d_in[5];
    const float* emb    = (const float*)d_in[6];

    const int n_tokens = in_sizes[0];              // 4096*200 = 819200
    float* out_sum = (float*)d_out;                // [n_tokens, 128]
    float* out_pm  = (float*)d_out + (long long)n_tokens * EMB;  // [n_tokens]

    const int waves_needed  = (n_tokens + 1) / 2;
    const int blocks_needed = (waves_needed + 3) / 4;
    const int grid = blocks_needed < 2048 ? blocks_needed : 2048;

    tabenc_kernel<<<grid, 256, 0, stream>>>(value, var_id, cmask, W1, b1, W2,
                                            emb, out_sum, out_pm, n_tokens);
}

// Round 12
// 96.464 us; speedup vs baseline: 3.9352x; 3.9352x over previous
//
#include <hip/hip_runtime.h>
#include <hip/hip_bf16.h>

#define EMB 128
#define HID 11
#define PAIRS 2   // pair-units per stage; stage = 4 CONSECUTIVE tokens

typedef float f32x4 __attribute__((ext_vector_type(4)));

// tanh(x) = sign(x) * (1 - 2/(exp(2|x|)+1)); v_exp_f32 + v_rcp_f32 fast path.
__device__ __forceinline__ float fast_tanh(float x) {
    float ax = fabsf(x);
    float e  = __expf(2.0f * ax);
    float r  = 1.0f - 2.0f * __builtin_amdgcn_rcpf(e + 1.0f);
    return copysignf(r, x);
}

// Locked-in: NT stores for out_sum (R7: plain = +46us), dense instantaneous
// write front (R6), no tight VGPR cap (R3), depth-1 pipeline (R5).
// R12 change: stage = 4 CONSECUTIVE tokens (group-strided map, group stride =
// nwaves groups -> adjacent waves still write adjacent 2KB chunks = dense
// front). Benefits: (a) out_sum = one contiguous 2KB NT burst per stage;
// (b) pm for the 4 tokens assembled in-register (2 cross-half shfls) into ONE
// float4 NT store -> ZERO masked partial-line dword stores in the kernel
// (R11 diagnosis: 400K masked pm dword stores false-shared across XCDs were
// the prime suspect for the 3.8 vs 6.9 TB/s store-drain gap).
// Wave layout per pair-unit k: lanes 0..31 -> token 4g+2k, lanes 32..63 ->
// token 4g+2k+1; lane covers 4 emb columns, c0=(lane&31)*4.
__global__ __launch_bounds__(256, 2) void tabenc_kernel(
    const float* __restrict__ value,
    const int*   __restrict__ var_id,
    const int*   __restrict__ cmask,
    const float* __restrict__ W1,
    const float* __restrict__ b1,
    const float* __restrict__ W2,
    const float* __restrict__ emb,
    float*       __restrict__ out_sum,
    float*       __restrict__ out_pm,
    int n_tokens)
{
    const int tid  = threadIdx.x;
    const int lane = tid & 63;
    const int half = lane >> 5;
    const int sub  = lane & 31;
    const int sb   = lane & 32;      // shfl source base for this half-wave
    const int c0   = sub << 2;

    f32x4 w2[HID];
#pragma unroll
    for (int h = 0; h < HID; ++h)
        w2[h] = *reinterpret_cast<const f32x4*>(W2 + h * EMB + c0);

    float w1v = 0.0f, b1v = 0.0f;
    if (sub < HID) { w1v = W1[sub]; b1v = b1[sub]; }

    const int gwave  = (blockIdx.x << 2) + (tid >> 6);
    const int nwaves = gridDim.x << 2;
    const int ngrp   = (n_tokens + 3) >> 2;   // groups of 4 consecutive tokens
    const int tmax   = n_tokens - 1;

    if (gwave >= ngrp) return;

    int   tokC[PAIRS]; float vC[PAIRS]; int idC[PAIRS];
    float fmC[PAIRS];  f32x4 eC[PAIRS];
    int   tokN[PAIRS]; float vN[PAIRS]; int idN[PAIRS];
    float fmN[PAIRS];  f32x4 eN[PAIRS];

    auto LOAD = [&](int g, int* tok, float* v, int* id, float* fm, f32x4* e) {
#pragma unroll
        for (int k = 0; k < PAIRS; ++k) {
            int t = (g << 2) + (k << 1) + half;
            if (t > tmax) t = tmax;     // clamp: branch-free, dup loads only
            tok[k] = t;
            v[k]  = value[t];
            id[k] = var_id[t];
            fm[k] = (float)cmask[t];
        }
#pragma unroll
        for (int k = 0; k < PAIRS; ++k)
            e[k] = *reinterpret_cast<const f32x4*>(emb + (long)id[k] * EMB + c0);
    };

    LOAD(gwave, tokC, vC, idC, fmC, eC);

    for (int g = gwave; g < ngrp; g += nwaves) {
        // ---- prefetch next stage (clamped, unconditional) ----
        LOAD(g + nwaves, tokN, vN, idN, fmN, eN);

        // ---- compute current stage ----
        float hv[PAIRS];
#pragma unroll
        for (int k = 0; k < PAIRS; ++k)
            hv[k] = fast_tanh(fmaf(vC[k], w1v, b1v));

        f32x4 acc[PAIRS];
#pragma unroll
        for (int k = 0; k < PAIRS; ++k)
            acc[k] = (f32x4){0.f, 0.f, 0.f, 0.f};

#pragma unroll
        for (int hh = 0; hh < HID; ++hh) {
#pragma unroll
            for (int k = 0; k < PAIRS; ++k) {
                const float kk = __shfl(hv[k], sb + hh, 64);
                acc[k] += kk * w2[hh];
            }
        }

        const int t0 = g << 2;                 // first token of this group
        const bool full = (t0 + 3 <= tmax);    // group fully in range

        // ---- out_sum: one contiguous 2KB NT burst (4 x dwordx4/lane) ----
#pragma unroll
        for (int k = 0; k < PAIRS; ++k) {
            if (full || tokC[k] == t0 + (k << 1) + half)  // in-range check
                __builtin_nontemporal_store(acc[k] * fmC[k] + eC[k],
                    reinterpret_cast<f32x4*>(out_sum + (long)tokC[k] * EMB + c0));
        }

        // ---- out_pm: one float4 NT store (no masked dword stores) ----
        // lane 0 holds ids for tokens t0 (k=0) and t0+2 (k=1); lane 32 holds
        // t0+1 and t0+3. Two cross-half shfls assemble all four.
        {
            const float pA = (idC[0] > 0) ? 1.0f : 0.0f;   // t0 + half
            const float pB = (idC[1] > 0) ? 1.0f : 0.0f;   // t0 + 2 + half
            const float pA1 = __shfl(pA, 32, 64);          // t0 + 1
            const float pB1 = __shfl(pB, 32, 64);          // t0 + 3
            if (lane == 0) {
                if (full) {
                    const f32x4 pm = (f32x4){pA, pA1, pB, pB1};
                    __builtin_nontemporal_store(pm,
                        reinterpret_cast<f32x4*>(out_pm + t0));
                } else {                       // tail group (never for 819200)
                    const float pv[4] = {pA, pA1, pB, pB1};
                    for (int t = t0; t <= tmax; ++t) out_pm[t] = pv[t - t0];
                }
            }
        }

        // ---- rotate pipeline regs ----
#pragma unroll
        for (int k = 0; k < PAIRS; ++k) {
            tokC[k] = tokN[k]; vC[k] = vN[k];
            idC[k]  = idN[k];  fmC[k] = fmN[k]; eC[k] = eN[k];
        }
    }
}

extern "C" void kernel_launch(void* const* d_in, const int* in_sizes, int n_in,
                              void* d_out, int out_size, void* d_ws, size_t ws_size,
                              hipStream_t stream) {
    const float* value  = (const float*)d_in[0];
    const int*   var_id = (const int*)  d_in[1];
    const int*   cmask  = (const int*)  d_in[2];
    const float* W1     = (const float*)d_in[3];
    const float* b1     = (const float*)d_in[4];
    const float* W2     = (const float*)d_in[5];
    const float* emb    = (const float*)d_in[6];

    const int n_tokens = in_sizes[0];              // 4096*200 = 819200
    float* out_sum = (float*)d_out;                // [n_tokens, 128]
    float* out_pm  = (float*)d_out + (long long)n_tokens * EMB;  // [n_tokens]

    const int groups_needed = (n_tokens + 3) / 4;
    const int blocks_needed = (groups_needed + 3) / 4;
    const int grid = blocks_needed < 2048 ? blocks_needed : 2048;

    tabenc_kernel<<<grid, 256, 0, stream>>>(value, var_id, cmask, W1, b1, W2,
                                            emb, out_sum, out_pm, n_tokens);
}